// Round 3
// baseline (218.057 us; speedup 1.0000x reference)
//
#include <hip/hip_runtime.h>
#include <math.h>

namespace {
constexpr int S = 7;
constexpr int PF = 30;   // floats per cell, predictions
constexpr int TF = 25;   // floats per cell, targets
constexpr int C = 20;
constexpr float EPS = 1e-6f;
constexpr float LAMBDA_COORD = 5.0f;
constexpr float LAMBDA_NOOBJ = 0.5f;
constexpr int BLK = 256;
constexpr int ILP = 4;       // float4s per thread per tile
constexpr int NBLK = 2048;   // fixed grid; part[] = NBLK*4 floats = 32 KB
}

// Unified coalesced float4 scan over pred then tgt (one flat index space).
// Pred path: sum conf^2 (positions q%15 in {1,2,8,9} -> elements x,y,z,w).
// Tgt path: detect t4 (positions q%25 in {1,7,13,19}); obj lanes (~6%)
// gather their cell's 55 floats (lines are cache-hot from the stream) and
// compute coord / conf_obj / class, subtracting resp conf^2 from noobj.
__global__ __launch_bounds__(BLK) void k_scan(const float* __restrict__ pred,
                                              const float* __restrict__ tgt,
                                              float* __restrict__ part,
                                              unsigned np4p, unsigned np4t) {
    const unsigned tid = threadIdx.x;
    const unsigned total = np4p + np4t;
    const unsigned tile = BLK * ILP;

    float v0 = 0.f, v1 = 0.f, v2 = 0.f, v3 = 0.f;

    for (unsigned start = blockIdx.x * tile; start < total; start += gridDim.x * tile) {
        float4 val[ILP];
        unsigned qv[ILP];
        bool okv[ILP], ispv[ILP];
        #pragma unroll
        for (int k = 0; k < ILP; ++k) {
            const unsigned idx = start + (unsigned)k * BLK + tid;
            const bool ok = idx < total;
            const bool isp = idx < np4p;
            const unsigned q = isp ? idx : (idx - np4p);
            okv[k] = ok; ispv[k] = isp; qv[k] = q;
            const float4* src = isp ? (const float4*)pred : (const float4*)tgt;
            val[k] = ok ? src[q] : make_float4(0.f, 0.f, 0.f, 0.f);
        }
        #pragma unroll
        for (int k = 0; k < ILP; ++k) {
            if (!okv[k]) continue;
            const float4 v = val[k];
            const unsigned q = qv[k];
            if (ispv[k]) {
                const unsigned r = q % 15u;
                const float s = (r == 1u) ? v.x
                              : (r == 2u) ? v.y
                              : (r == 8u) ? v.z
                              : (r == 9u) ? v.w : 0.f;
                v2 += s * s;
            } else {
                const unsigned r = q % 25u;
                const unsigned m = q / 25u;
                float t4 = 0.f; unsigned cell = 0u;
                if (r == 1u)       { t4 = v.x; cell = 4u * m; }
                else if (r == 7u)  { t4 = v.y; cell = 4u * m + 1u; }
                else if (r == 13u) { t4 = v.z; cell = 4u * m + 2u; }
                else if (r == 19u) { t4 = v.w; cell = 4u * m + 3u; }
                if (t4 > 0.f) {
                    const float* p = pred + (size_t)cell * PF;
                    const float* t = tgt + (size_t)cell * TF;
                    const unsigned j = cell % 7u;
                    const unsigned i = (cell / 7u) % 7u;
                    const float invS = 1.0f / 7.0f;

                    const float2 p01 = *(const float2*)(p + 0);
                    const float2 p23 = *(const float2*)(p + 2);
                    const float2 p45 = *(const float2*)(p + 4);
                    const float2 p67 = *(const float2*)(p + 6);
                    const float2 p89 = *(const float2*)(p + 8);
                    const float gx = t[0], gy = t[1], gw = t[2], gh = t[3];

                    const float gcx = ((float)j + gx) * invS;
                    const float gcy = ((float)i + gy) * invS;
                    const float gx1 = gcx - gw * 0.5f, gy1 = gcy - gh * 0.5f;
                    const float gx2 = gcx + gw * 0.5f, gy2 = gcy + gh * 0.5f;
                    const float garea = (gx2 - gx1) * (gy2 - gy1);

                    const float bx[2]  = {p01.x, p45.y};
                    const float by[2]  = {p01.y, p67.x};
                    const float bw_[2] = {p23.x, p67.y};
                    const float bh[2]  = {p23.y, p89.x};
                    const float cf[2]  = {p45.x, p89.y};
                    float iou[2];
                    #pragma unroll
                    for (int b = 0; b < 2; ++b) {
                        const float cx = ((float)j + bx[b]) * invS;
                        const float cy = ((float)i + by[b]) * invS;
                        const float x1 = cx - bw_[b] * 0.5f, y1 = cy - bh[b] * 0.5f;
                        const float x2 = cx + bw_[b] * 0.5f, y2 = cy + bh[b] * 0.5f;
                        const float ix1 = fmaxf(x1, gx1), iy1 = fmaxf(y1, gy1);
                        const float ix2 = fminf(x2, gx2), iy2 = fminf(y2, gy2);
                        const float inter = fmaxf(ix2 - ix1, 0.f) * fmaxf(iy2 - iy1, 0.f);
                        const float parea = (x2 - x1) * (y2 - y1);
                        iou[b] = inter / (parea + garea - inter + EPS);
                    }
                    const int best = (iou[1] > iou[0]) ? 1 : 0;   // first max wins
                    const float rconf = cf[best], riou = iou[best];

                    const float dx = bx[best] - gx, dy = by[best] - gy;
                    const float swd = sqrtf(bw_[best] + EPS) - sqrtf(gw + EPS);
                    const float shd = sqrtf(bh[best] + EPS) - sqrtf(gh + EPS);
                    v0 += dx*dx + dy*dy + swd*swd + shd*shd;
                    const float dc = rconf - riou;
                    v1 += dc * dc;
                    v2 -= rconf * rconf;

                    float se = 0.f, dot = 0.f, sg = 0.f;
                    #pragma unroll
                    for (int c = 0; c < C; c += 2) {
                        const float2 lc = *(const float2*)(p + 10 + c);
                        const float g0 = t[5 + c], g1 = t[6 + c];
                        se  += __expf(lc.x) + __expf(lc.y);
                        dot += g0 * lc.x + g1 * lc.y;
                        sg  += g0 + g1;
                    }
                    v3 += __logf(se) * sg - dot;
                }
            }
        }
    }

    // ---- reduce: wave64 butterfly -> LDS -> per-block partial slot ----
    float v[4] = {v0, v1, v2, v3};
    #pragma unroll
    for (int off = 32; off >= 1; off >>= 1) {
        v[0] += __shfl_down(v[0], off, 64);
        v[1] += __shfl_down(v[1], off, 64);
        v[2] += __shfl_down(v[2], off, 64);
        v[3] += __shfl_down(v[3], off, 64);
    }
    __shared__ float red[16];
    const int lane = tid & 63;
    const int wave = tid >> 6;
    if (lane == 0) {
        red[wave * 4 + 0] = v[0];
        red[wave * 4 + 1] = v[1];
        red[wave * 4 + 2] = v[2];
        red[wave * 4 + 3] = v[3];
    }
    __syncthreads();
    if (tid < 4)
        part[blockIdx.x * 4 + tid] =
            red[tid] + red[4 + tid] + red[8 + tid] + red[12 + tid];
}

// Single block: reduce NBLK x 4 partials, write 5 outputs.
__global__ __launch_bounds__(BLK) void k_fin(const float* __restrict__ part,
                                             float* __restrict__ out,
                                             int nblk, float n) {
    const int tid = threadIdx.x;
    float a0 = 0.f, a1 = 0.f, a2 = 0.f, a3 = 0.f;
    for (int r = tid; r < nblk; r += BLK) {
        const float4 q = *(const float4*)(part + r * 4);
        a0 += q.x; a1 += q.y; a2 += q.z; a3 += q.w;
    }
    float v[4] = {a0, a1, a2, a3};
    #pragma unroll
    for (int off = 32; off >= 1; off >>= 1) {
        v[0] += __shfl_down(v[0], off, 64);
        v[1] += __shfl_down(v[1], off, 64);
        v[2] += __shfl_down(v[2], off, 64);
        v[3] += __shfl_down(v[3], off, 64);
    }
    __shared__ float red[16];
    const int lane = tid & 63;
    const int wave = tid >> 6;
    if (lane == 0) {
        red[wave * 4 + 0] = v[0];
        red[wave * 4 + 1] = v[1];
        red[wave * 4 + 2] = v[2];
        red[wave * 4 + 3] = v[3];
    }
    __syncthreads();
    if (tid == 0) {
        const float coord  = red[0] + red[4] + red[8] + red[12];
        const float cobj   = red[1] + red[5] + red[9] + red[13];
        const float cnoobj = red[2] + red[6] + red[10] + red[14];
        const float ccls   = red[3] + red[7] + red[11] + red[15];
        const float inv = 1.0f / n;
        out[0] = coord * inv;
        out[1] = cobj * inv;
        out[2] = cnoobj * inv;
        out[3] = ccls * inv;
        out[4] = (LAMBDA_COORD * coord + cobj + LAMBDA_NOOBJ * cnoobj + ccls) * inv;
    }
}

extern "C" void kernel_launch(void* const* d_in, const int* in_sizes, int n_in,
                              void* d_out, int out_size, void* d_ws, size_t ws_size,
                              hipStream_t stream) {
    const float* pred = (const float*)d_in[0];
    const float* tgt  = (const float*)d_in[1];
    float* out  = (float*)d_out;
    float* part = (float*)d_ws;

    const unsigned np4p = (unsigned)(in_sizes[0] / 4);   // 6,021,120
    const unsigned np4t = (unsigned)(in_sizes[1] / 4);   // 5,017,600
    const int n_cells = in_sizes[0] / PF;
    const float bs = (float)(n_cells / (S * S));         // 16384

    k_scan<<<NBLK, BLK, 0, stream>>>(pred, tgt, part, np4p, np4t);
    k_fin<<<1, BLK, 0, stream>>>(part, out, NBLK, bs);
}